// Round 2
// 1077.519 us; speedup vs baseline: 1.2734x; 1.2734x over previous
//
#include <hip/hip_runtime.h>
#include <stdint.h>

#define CIN  16
#define COUT 32
#define K2   9

typedef __attribute__((ext_vector_type(8)))  short bf16x8;   // 8 bf16 = 4 VGPR (MFMA A/B frag)
typedef __attribute__((ext_vector_type(16))) float f32x16;   // MFMA 32x32 C/D frag
typedef __attribute__((ext_vector_type(4)))  float f32x4;

// ---------- bf16 helpers (RNE) ----------
__device__ __forceinline__ uint16_t f2bf(float f) {
    union { float f; uint32_t u; } a; a.f = f;
    uint32_t u = a.u;
    uint32_t r = u + 0x7FFFu + ((u >> 16) & 1u);
    return (uint16_t)(r >> 16);
}
__device__ __forceinline__ float bf2f(uint32_t b16) {
    union { uint32_t u; float f; } a; a.u = b16 << 16; return a.f;
}

// ---------- mask-width detection + zero-row init ----------
// nbr_mask row k=4 (center) is all-true. If int32 mask, words [4n,4n+64) are
// all exactly 1; if byte mask those words are random 0/1 byte packs -> ~never
// all 1. flag=1 -> int32 mask, flag=0 -> byte mask. (Proven in prior session.)
// Also zero a 64B "zero row" used to redirect masked-off gathers.
__global__ void detect_mask_kernel(const uint32_t* __restrict__ mw,
                                   int* __restrict__ flag,
                                   float* __restrict__ zrow, int n) {
    int t = threadIdx.x;
    uint32_t w = mw[(size_t)4 * (size_t)n + (size_t)t];
    unsigned long long b = __ballot(w == 1u);
    if (t == 0) *flag = (b == ~0ull) ? 1 : 0;
    if (t < 16) zrow[t] = 0.0f;
}

// Build a B-fragment (B[K=16][N=32]) for v_mfma_f32_32x32x16_bf16 from f32
// weights W[ch][col] with row stride COUT. Lane l holds B[8*(l>>5)+e][l&31].
// One-time per wave; coalesced f32 reads (col = consecutive lanes).
__device__ __forceinline__ bf16x8 make_bfrag(const float* __restrict__ W,
                                             int chbase, int col, int half) {
    bf16x8 f;
    #pragma unroll
    for (int e = 0; e < 8; ++e)
        f[e] = (short)f2bf(W[(chbase + half * 8 + e) * COUT + col]);
    return f;
}

// ---------- conv1 + relu -> h (bf16) ----------
// Per wave: 32-voxel tile. A[32 vox x 16 cin] gathered from x (f32 rows, 32B
// per lane = exact row coverage by 2 lanes), split hi/lo bf16 for f32-accurate
// input. One 32x32x16 MFMA pair per offset. C: col=lane&31,
// row=(reg&3)+8*(reg>>2)+4*(lane>>5).
__global__ void __launch_bounds__(256, 4)
conv1_kernel(const float* __restrict__ x,
             const float* __restrict__ W1,
             const float* __restrict__ b1,
             const int*   __restrict__ nidx,
             const void*  __restrict__ nmask,
             const int*   __restrict__ mflag,
             const char*  __restrict__ zrow,
             uint16_t*    __restrict__ hbuf,
             int n)
{
    const int lane = threadIdx.x & 63;
    const int wid  = threadIdx.x >> 6;
    const int col  = lane & 31;
    const int half = lane >> 5;
    const int mode32 = *mflag;
    const int*     m32 = (const int*)nmask;
    const uint8_t* m8  = (const uint8_t*)nmask;

    bf16x8 Bf[K2];
    #pragma unroll
    for (int k = 0; k < K2; ++k)
        Bf[k] = make_bfrag(W1 + k * (CIN * COUT), 0, col, half);
    const float bias = b1[col];

    const int ntiles = (n + 31) >> 5;
    for (int tile = blockIdx.x * 4 + wid; tile < ntiles; tile += gridDim.x * 4) {
        const int vbase = tile << 5;
        const int vr = vbase + col;
        const int vc = (vr < n) ? vr : (n - 1);

        int idv[K2];
        uint32_t mb = 0;
        #pragma unroll
        for (int k = 0; k < K2; ++k) {
            const size_t e = (size_t)k * (size_t)n + (size_t)vc;
            idv[k] = __builtin_nontemporal_load(nidx + e);
            const int m = mode32 ? (__builtin_nontemporal_load(m32 + e) != 0)
                                 : (__builtin_nontemporal_load(m8  + e) != 0);
            mb |= (uint32_t)m << k;
        }

        f32x16 acc = {};

        // 1-ahead pipelined gather of x rows (masked -> zero row, stays L1-hot)
        f32x4 xa = {}, xb = {}, xa1 = {}, xb1 = {};
        {
            const float* p = (mb & 1u)
                ? (x + (size_t)(uint32_t)idv[0] * CIN + half * 8)
                : (const float*)(zrow + half * 32);
            xa = ((const f32x4*)p)[0];
            xb = ((const f32x4*)p)[1];
        }
        #pragma unroll
        for (int k = 0; k < K2; ++k) {
            if (k + 1 < K2) {
                const float* p = ((mb >> (k + 1)) & 1u)
                    ? (x + (size_t)(uint32_t)idv[k + 1] * CIN + half * 8)
                    : (const float*)(zrow + half * 32);
                xa1 = ((const f32x4*)p)[0];
                xb1 = ((const f32x4*)p)[1];
            }
            bf16x8 hi, lo;
            #pragma unroll
            for (int e = 0; e < 8; ++e) {
                const float xv = (e < 4) ? xa[e] : xb[e - 4];
                const uint16_t hb = f2bf(xv);
                hi[e] = (short)hb;
                lo[e] = (short)f2bf(xv - bf2f(hb));
            }
            acc = __builtin_amdgcn_mfma_f32_32x32x16_bf16(hi, Bf[k], acc, 0, 0, 0);
            acc = __builtin_amdgcn_mfma_f32_32x32x16_bf16(lo, Bf[k], acc, 0, 0, 0);
            xa = xa1; xb = xb1;
        }

        #pragma unroll
        for (int r = 0; r < 16; ++r) {
            const int row = (r & 3) + 8 * (r >> 2) + 4 * half;
            const int vo = vbase + row;
            if (vo < n) {
                const float o = fmaxf(acc[r] + bias, 0.0f);
                hbuf[(size_t)vo * COUT + col] = f2bf(o);   // regular store: keep h in L3 for conv2
            }
        }
    }
}

// ---------- conv2 + residual proj + relu -> out ----------
// Per wave: 32-voxel tile. h rows (64B bf16) gather DIRECTLY into A-frags:
// lane l loads 16B at (half*16) and (32+half*16) of row idv[k] -> exactly the
// A[32x16] fragments for channel halves 0-15 / 16-31. Residual x@Wp via hi/lo
// split MFMA.
__global__ void __launch_bounds__(256, 3)
conv2_kernel(const float* __restrict__ x,
             const float* __restrict__ W2,
             const float* __restrict__ b2,
             const float* __restrict__ Wp,
             const float* __restrict__ bp,
             const int*   __restrict__ nidx,
             const void*  __restrict__ nmask,
             const int*   __restrict__ mflag,
             const char*  __restrict__ zrow,
             const uint16_t* __restrict__ hbuf,
             float*       __restrict__ out,
             int n)
{
    const int lane = threadIdx.x & 63;
    const int wid  = threadIdx.x >> 6;
    const int col  = lane & 31;
    const int half = lane >> 5;
    const int mode32 = *mflag;
    const int*     m32 = (const int*)nmask;
    const uint8_t* m8  = (const uint8_t*)nmask;

    bf16x8 Bf0[K2], Bf1[K2];
    #pragma unroll
    for (int k = 0; k < K2; ++k) {
        Bf0[k] = make_bfrag(W2 + k * (COUT * COUT), 0,  col, half);
        Bf1[k] = make_bfrag(W2 + k * (COUT * COUT), 16, col, half);
    }
    const bf16x8 Bp = make_bfrag(Wp, 0, col, half);   // CIN=16 rows
    const float bias = b2[col] + bp[col];

    const int ntiles = (n + 31) >> 5;
    for (int tile = blockIdx.x * 4 + wid; tile < ntiles; tile += gridDim.x * 4) {
        const int vbase = tile << 5;
        const int vr = vbase + col;
        const int vc = (vr < n) ? vr : (n - 1);

        int idv[K2];
        uint32_t mb = 0;
        #pragma unroll
        for (int k = 0; k < K2; ++k) {
            const size_t e = (size_t)k * (size_t)n + (size_t)vc;
            idv[k] = __builtin_nontemporal_load(nidx + e);
            const int m = mode32 ? (__builtin_nontemporal_load(m32 + e) != 0)
                                 : (__builtin_nontemporal_load(m8  + e) != 0);
            mb |= (uint32_t)m << k;
        }

        f32x16 acc = {};

        // residual x[i] @ Wp, hi/lo split (effectively f32-accurate), nt loads
        {
            const f32x4* xr = (const f32x4*)(x + (size_t)vc * CIN + half * 8);
            const f32x4 xa = __builtin_nontemporal_load(xr);
            const f32x4 xb = __builtin_nontemporal_load(xr + 1);
            bf16x8 hi, lo;
            #pragma unroll
            for (int e = 0; e < 8; ++e) {
                const float xv = (e < 4) ? xa[e] : xb[e - 4];
                const uint16_t hb = f2bf(xv);
                hi[e] = (short)hb;
                lo[e] = (short)f2bf(xv - bf2f(hb));
            }
            acc = __builtin_amdgcn_mfma_f32_32x32x16_bf16(hi, Bp, acc, 0, 0, 0);
            acc = __builtin_amdgcn_mfma_f32_32x32x16_bf16(lo, Bp, acc, 0, 0, 0);
        }

        // 1-ahead pipelined h-row gathers straight into A-fragments
        bf16x8 A0, A1, N0 = {}, N1 = {};
        {
            const char* p = (mb & 1u)
                ? (const char*)hbuf + (size_t)(uint32_t)idv[0] * (COUT * 2)
                : zrow;
            A0 = *(const bf16x8*)(p + half * 16);
            A1 = *(const bf16x8*)(p + 32 + half * 16);
        }
        #pragma unroll
        for (int k = 0; k < K2; ++k) {
            if (k + 1 < K2) {
                const char* p = ((mb >> (k + 1)) & 1u)
                    ? (const char*)hbuf + (size_t)(uint32_t)idv[k + 1] * (COUT * 2)
                    : zrow;
                N0 = *(const bf16x8*)(p + half * 16);
                N1 = *(const bf16x8*)(p + 32 + half * 16);
            }
            acc = __builtin_amdgcn_mfma_f32_32x32x16_bf16(A0, Bf0[k], acc, 0, 0, 0);
            acc = __builtin_amdgcn_mfma_f32_32x32x16_bf16(A1, Bf1[k], acc, 0, 0, 0);
            A0 = N0; A1 = N1;
        }

        #pragma unroll
        for (int r = 0; r < 16; ++r) {
            const int row = (r & 3) + 8 * (r >> 2) + 4 * half;
            const int vo = vbase + row;
            if (vo < n) {
                const float o = fmaxf(acc[r] + bias, 0.0f);
                __builtin_nontemporal_store(o, out + (size_t)vo * COUT + col);
            }
        }
    }
}

extern "C" void kernel_launch(void* const* d_in, const int* in_sizes, int n_in,
                              void* d_out, int out_size, void* d_ws, size_t ws_size,
                              hipStream_t stream) {
    const float* x    = (const float*)d_in[0];
    const float* W1   = (const float*)d_in[1];
    const float* b1   = (const float*)d_in[2];
    const float* W2   = (const float*)d_in[3];
    const float* b2   = (const float*)d_in[4];
    const float* Wp   = (const float*)d_in[5];
    const float* bp   = (const float*)d_in[6];
    const int*   nidx = (const int*)d_in[7];
    const void*  nmask = d_in[8];
    const int n = in_sizes[0] / CIN;

    int*      mflag = (int*)d_ws;                       // [0,4): mask-mode flag
    float*    zrowf = (float*)((char*)d_ws + 64);       // [64,128): 64B zero row
    uint16_t* hbuf  = (uint16_t*)((char*)d_ws + 256);   // bf16 h [n][32]

    detect_mask_kernel<<<1, 64, 0, stream>>>((const uint32_t*)nmask, mflag, zrowf, n);

    const int ntiles = (n + 31) / 32;
    int grid = (ntiles + 3) / 4;
    if (grid > 1024) grid = 1024;

    conv1_kernel<<<grid, 256, 0, stream>>>(x, W1, b1, nidx, nmask, mflag,
                                           (const char*)zrowf, hbuf, n);
    conv2_kernel<<<grid, 256, 0, stream>>>(x, W2, b2, Wp, bp, nidx, nmask, mflag,
                                           (const char*)zrowf, hbuf, (float*)d_out, n);
}

// Round 3
// 1007.312 us; speedup vs baseline: 1.3621x; 1.0697x over previous
//
#include <hip/hip_runtime.h>
#include <stdint.h>

#define CIN  16
#define COUT 32
#define K2   9

typedef __attribute__((ext_vector_type(8)))  short bf16x8;   // 8 bf16 = 4 VGPR (MFMA A/B frag)
typedef __attribute__((ext_vector_type(16))) float f32x16;   // MFMA 32x32 C/D frag
typedef __attribute__((ext_vector_type(4)))  float f32x4;

// ---------- bf16 helpers (RNE) ----------
__device__ __forceinline__ uint16_t f2bf(float f) {
    union { float f; uint32_t u; } a; a.f = f;
    uint32_t u = a.u;
    uint32_t r = u + 0x7FFFu + ((u >> 16) & 1u);
    return (uint16_t)(r >> 16);
}
__device__ __forceinline__ float bf2f(uint32_t b16) {
    union { uint32_t u; float f; } a; a.u = b16 << 16; return a.f;
}

// ---------- mask-width detection + zero-row init (proven on this harness) ----------
__global__ void detect_mask_kernel(const uint32_t* __restrict__ mw,
                                   int* __restrict__ flag,
                                   float* __restrict__ zrow, int n) {
    int t = threadIdx.x;
    uint32_t w = mw[(size_t)4 * (size_t)n + (size_t)t];
    unsigned long long b = __ballot(w == 1u);
    if (t == 0) *flag = (b == ~0ull) ? 1 : 0;
    if (t < 16) zrow[t] = 0.0f;
}

// ---------- conv1 + relu -> h (bf16) ----------
// Weights in LDS (bf16 frag layout, one ds_read_b128 per B-frag).
// All 9 x-row gathers issued before the MFMA chain (18 outstanding 16B loads).
// A-frag: lane l holds A[row=l&31][k=8*(l>>5)+e]; C/D: col=lane&31,
// row=(reg&3)+8*(reg>>2)+4*(lane>>5). (Layouts harness-verified in round 2.)
__global__ void __launch_bounds__(256, 4)
conv1_kernel(const float* __restrict__ x,
             const float* __restrict__ W1,
             const float* __restrict__ b1,
             const int*   __restrict__ nidx,
             const void*  __restrict__ nmask,
             const int*   __restrict__ mflag,
             const char*  __restrict__ zrow,
             uint16_t*    __restrict__ hbuf,
             int n)
{
    __shared__ __align__(16) uint16_t smw[K2 * 2 * 32 * 8];   // 9216 B: [k][half][col][e]

    // cooperative weight convert: one-time per block, amortized over ~8 tiles/wave
    for (int i = threadIdx.x; i < K2 * 2 * 32 * 8; i += 256) {
        const int e = i & 7, c2 = (i >> 3) & 31, hf = (i >> 8) & 1, k = i >> 9;
        smw[i] = f2bf(W1[k * (CIN * COUT) + (hf * 8 + e) * COUT + c2]);
    }
    __syncthreads();

    const int lane = threadIdx.x & 63;
    const int wid  = threadIdx.x >> 6;
    const int col  = lane & 31;
    const int half = lane >> 5;
    const int mode32 = *mflag;
    const int*     m32 = (const int*)nmask;
    const uint8_t* m8  = (const uint8_t*)nmask;

    const float bias = b1[col];
    const int ntiles = (n + 31) >> 5;

    for (int tile = blockIdx.x * 4 + wid; tile < ntiles; tile += gridDim.x * 4) {
        const int vbase = tile << 5;
        const int vr = vbase + col;
        const int vc = (vr < n) ? vr : (n - 1);

        int idv[K2];
        uint32_t mb = 0;
        #pragma unroll
        for (int k = 0; k < K2; ++k) {
            const size_t e = (size_t)k * (size_t)n + (size_t)vc;
            idv[k] = __builtin_nontemporal_load(nidx + e);
            const int m = mode32 ? (__builtin_nontemporal_load(m32 + e) != 0)
                                 : (__builtin_nontemporal_load(m8  + e) != 0);
            mb |= (uint32_t)m << k;
        }

        // issue ALL 9 row gathers (18 x 16B) before any compute
        f32x4 ga[K2], gb[K2];
        #pragma unroll
        for (int k = 0; k < K2; ++k) {
            const float* p = ((mb >> k) & 1u)
                ? (x + (size_t)(uint32_t)idv[k] * CIN + half * 8)
                : (const float*)(zrow + half * 32);
            ga[k] = ((const f32x4*)p)[0];
            gb[k] = ((const f32x4*)p)[1];
        }

        f32x16 acc = {};
        #pragma unroll
        for (int k = 0; k < K2; ++k) {
            const bf16x8 Bf = *(const bf16x8*)&smw[((k * 2 + half) * 32 + col) * 8];
            bf16x8 hi, lo;
            #pragma unroll
            for (int e = 0; e < 8; ++e) {
                const float xv = (e < 4) ? ga[k][e] : gb[k][e - 4];
                const uint16_t hb = f2bf(xv);
                hi[e] = (short)hb;
                lo[e] = (short)f2bf(xv - bf2f(hb));
            }
            acc = __builtin_amdgcn_mfma_f32_32x32x16_bf16(hi, Bf, acc, 0, 0, 0);
            acc = __builtin_amdgcn_mfma_f32_32x32x16_bf16(lo, Bf, acc, 0, 0, 0);
        }

        #pragma unroll
        for (int r = 0; r < 16; ++r) {
            const int row = (r & 3) + 8 * (r >> 2) + 4 * half;
            const int vo = vbase + row;
            if (vo < n) {
                const float o = fmaxf(acc[r] + bias, 0.0f);
                hbuf[(size_t)vo * COUT + col] = f2bf(o);   // regular store: keep h in L3
            }
        }
    }
}

// ---------- conv2 + residual proj + relu -> out ----------
// h-row gathers (64B bf16) land directly in A-frags; all 9 offsets (18 x 16B)
// in flight before the MFMA chain. Weights (W2 + Wp) in LDS.
__global__ void __launch_bounds__(256, 4)
conv2_kernel(const float* __restrict__ x,
             const float* __restrict__ W2,
             const float* __restrict__ b2,
             const float* __restrict__ Wp,
             const float* __restrict__ bp,
             const int*   __restrict__ nidx,
             const void*  __restrict__ nmask,
             const int*   __restrict__ mflag,
             const char*  __restrict__ zrow,
             const uint16_t* __restrict__ hbuf,
             float*       __restrict__ out,
             int n)
{
    // [k][cb][half][col][e] for W2 (9216), then [half][col][e] for Wp (512)
    __shared__ __align__(16) uint16_t smw[K2 * 4 * 32 * 8 + 2 * 32 * 8];   // 19456 B

    for (int i = threadIdx.x; i < K2 * 4 * 32 * 8 + 2 * 32 * 8; i += 256) {
        uint16_t v;
        if (i < K2 * 4 * 32 * 8) {
            const int e = i & 7, c2 = (i >> 3) & 31, hf = (i >> 8) & 1,
                      cb = (i >> 9) & 1, k = i >> 10;
            v = f2bf(W2[k * (COUT * COUT) + (cb * 16 + hf * 8 + e) * COUT + c2]);
        } else {
            const int j = i - K2 * 4 * 32 * 8;
            const int e = j & 7, c2 = (j >> 3) & 31, hf = (j >> 8) & 1;
            v = f2bf(Wp[(hf * 8 + e) * COUT + c2]);
        }
        smw[i] = v;
    }
    __syncthreads();

    const int lane = threadIdx.x & 63;
    const int wid  = threadIdx.x >> 6;
    const int col  = lane & 31;
    const int half = lane >> 5;
    const int mode32 = *mflag;
    const int*     m32 = (const int*)nmask;
    const uint8_t* m8  = (const uint8_t*)nmask;

    const float bias = b2[col] + bp[col];
    const int ntiles = (n + 31) >> 5;

    for (int tile = blockIdx.x * 4 + wid; tile < ntiles; tile += gridDim.x * 4) {
        const int vbase = tile << 5;
        const int vr = vbase + col;
        const int vc = (vr < n) ? vr : (n - 1);

        int idv[K2];
        uint32_t mb = 0;
        #pragma unroll
        for (int k = 0; k < K2; ++k) {
            const size_t e = (size_t)k * (size_t)n + (size_t)vc;
            idv[k] = __builtin_nontemporal_load(nidx + e);
            const int m = mode32 ? (__builtin_nontemporal_load(m32 + e) != 0)
                                 : (__builtin_nontemporal_load(m8  + e) != 0);
            mb |= (uint32_t)m << k;
        }

        // residual x load (issued early, streamed once -> nt)
        const f32x4* xr = (const f32x4*)(x + (size_t)vc * CIN + half * 8);
        const f32x4 xa = __builtin_nontemporal_load(xr);
        const f32x4 xb = __builtin_nontemporal_load(xr + 1);

        // ALL 9 h-row gathers straight into A-frags (18 outstanding 16B loads)
        bf16x8 A0[K2], A1[K2];
        #pragma unroll
        for (int k = 0; k < K2; ++k) {
            const char* p = ((mb >> k) & 1u)
                ? (const char*)hbuf + (size_t)(uint32_t)idv[k] * (COUT * 2)
                : zrow;
            A0[k] = *(const bf16x8*)(p + half * 16);
            A1[k] = *(const bf16x8*)(p + 32 + half * 16);
        }

        f32x16 acc = {};

        // residual x[i] @ Wp, hi/lo split (effectively f32-accurate)
        {
            bf16x8 hi, lo;
            #pragma unroll
            for (int e = 0; e < 8; ++e) {
                const float xv = (e < 4) ? xa[e] : xb[e - 4];
                const uint16_t hb = f2bf(xv);
                hi[e] = (short)hb;
                lo[e] = (short)f2bf(xv - bf2f(hb));
            }
            const bf16x8 Bp = *(const bf16x8*)&smw[K2 * 4 * 32 * 8 + (half * 32 + col) * 8];
            acc = __builtin_amdgcn_mfma_f32_32x32x16_bf16(hi, Bp, acc, 0, 0, 0);
            acc = __builtin_amdgcn_mfma_f32_32x32x16_bf16(lo, Bp, acc, 0, 0, 0);
        }

        #pragma unroll
        for (int k = 0; k < K2; ++k) {
            const bf16x8 B0 = *(const bf16x8*)&smw[(((k * 2 + 0) * 2 + half) * 32 + col) * 8];
            const bf16x8 B1 = *(const bf16x8*)&smw[(((k * 2 + 1) * 2 + half) * 32 + col) * 8];
            acc = __builtin_amdgcn_mfma_f32_32x32x16_bf16(A0[k], B0, acc, 0, 0, 0);
            acc = __builtin_amdgcn_mfma_f32_32x32x16_bf16(A1[k], B1, acc, 0, 0, 0);
        }

        #pragma unroll
        for (int r = 0; r < 16; ++r) {
            const int row = (r & 3) + 8 * (r >> 2) + 4 * half;
            const int vo = vbase + row;
            if (vo < n) {
                const float o = fmaxf(acc[r] + bias, 0.0f);
                __builtin_nontemporal_store(o, out + (size_t)vo * COUT + col);
            }
        }
    }
}

extern "C" void kernel_launch(void* const* d_in, const int* in_sizes, int n_in,
                              void* d_out, int out_size, void* d_ws, size_t ws_size,
                              hipStream_t stream) {
    const float* x    = (const float*)d_in[0];
    const float* W1   = (const float*)d_in[1];
    const float* b1   = (const float*)d_in[2];
    const float* W2   = (const float*)d_in[3];
    const float* b2   = (const float*)d_in[4];
    const float* Wp   = (const float*)d_in[5];
    const float* bp   = (const float*)d_in[6];
    const int*   nidx = (const int*)d_in[7];
    const void*  nmask = d_in[8];
    const int n = in_sizes[0] / CIN;

    int*      mflag = (int*)d_ws;                       // [0,4): mask-mode flag
    float*    zrowf = (float*)((char*)d_ws + 64);       // [64,128): 64B zero row
    uint16_t* hbuf  = (uint16_t*)((char*)d_ws + 256);   // bf16 h [n][32]

    detect_mask_kernel<<<1, 64, 0, stream>>>((const uint32_t*)nmask, mflag, zrowf, n);

    const int ntiles = (n + 31) / 32;
    int grid = (ntiles + 3) / 4;
    if (grid > 2048) grid = 2048;

    conv1_kernel<<<grid, 256, 0, stream>>>(x, W1, b1, nidx, nmask, mflag,
                                           (const char*)zrowf, hbuf, n);
    conv2_kernel<<<grid, 256, 0, stream>>>(x, W2, b2, Wp, bp, nidx, nmask, mflag,
                                           (const char*)zrowf, hbuf, (float*)d_out, n);
}